// Round 6
// baseline (352.773 us; speedup 1.0000x reference)
//
#include <hip/hip_runtime.h>
#include <math.h>

// ---------------------------------------------------------------------------
// IPOT on MI355X — round 11.
// Math (exact, verified in R1-R10):
//   Cl = -C;  M_t = exp((t+1)*Cl)
//   row:  r_i = sum_j M_t(i,j) s_j ; a = 1/(n r)
//   col:  c_j = sum_i M_t(i,j) a_i ; b = 1/c (2^10 inj); s' = b^2/b_prev/1024
//   final G(A,B) = (1/(256*1024)) sum_k P(k,A) R(k,B)
// R11 (R10 refuted spill theory: VGPR=56 no-spill, still 4.85us/iter. The
//      remaining chain has TWO serialized same-address RMW ladders; remove
//      the readiness one entirely, halve the data one):
//   - k_ipot: per-WG monotonic FLAG (tid0 plain store t+1 to flg[g] after
//     drain barrier; wave0 polls all 32 flags, 1 load/lane, others parked
//     at barrier). Replaces the 4-group counter chain (8 serialized RMWs).
//   - NREP=8 replica groups (g&7): data atomicAdd chain depth 8 -> 4;
//     readback 8 loads (still 1 RT). Association change safe: iteration is
//     a contraction (absmax 0.0 across all nondeterministic variants).
//   - k_gemm: 1024 thr, 2x2 micro -> 16 waves/CU (was 8) to cover load
//     latency; staging split (tid<512 X / >=512 Y) keeps As/Bs contents,
//     k-order, and norm association BIT-IDENTICAL.
// ---------------------------------------------------------------------------

#define NWG 32
#define TPB 1024
#define NIT 50
#define NREP 8

typedef unsigned long long ull;

// ws offsets in floats
constexpr int CL_OFF   = 0;                           // -C [1024*1024]
constexpr int CVEC_OFF = 1024 * 1024;                 // [3][NREP][1024]
constexpr int FLG_OFF  = CVEC_OFF + 3 * NREP * 1024;  // [32] monotonic flags
// total ~ 4.1 MB

// ---------------- C = 1 - xhat yhat^T (norms fused) ; Cl = -C ---------------
__global__ __launch_bounds__(1024) void k_gemm(const float* __restrict__ X,
                                               const float* __restrict__ Y,
                                               float* __restrict__ ws) {
    __shared__ float As[32][68];
    __shared__ float Bs[32][68];
    __shared__ float nX[64], nY[64];
    float* Cl = ws + CL_OFF;

    int tid = threadIdx.x;
    int bx = blockIdx.x, by = blockIdx.y;

    // staging: tid<512 stages X rows, tid>=512 stages Y rows (same layout/k
    // order as R9/R10 -> bit-identical As/Bs contents)
    int st  = tid & 511;
    int lr0 = st >> 3;          // 0..63
    int kq  = (st & 7) * 4;     // 0..28
    const bool isX = tid < 512;
    const float* SRC = isX ? X : Y;
    int rcb = (isX ? by : bx) * 64;

    // compute: 2x2 micro-tile; rows 2*ty.., cols 2*tx..
    int tx = tid & 31, ty = tid >> 5;   // ty 0..31
    float acc[2][2] = {};
    float sn = 0.f;
    for (int k0 = 0; k0 < 512; k0 += 32) {
        float4 v = *(const float4*)(SRC + (size_t)(rcb + lr0) * 512 + k0 + kq);
        sn += v.x * v.x + v.y * v.y + v.z * v.z + v.w * v.w;
        float (*S)[68] = isX ? As : Bs;
        S[kq + 0][lr0] = v.x; S[kq + 1][lr0] = v.y;
        S[kq + 2][lr0] = v.z; S[kq + 3][lr0] = v.w;
        __syncthreads();
#pragma unroll
        for (int kk = 0; kk < 32; ++kk) {
            float2 a2 = *(const float2*)&As[kk][2 * ty];
            float2 b2 = *(const float2*)&Bs[kk][2 * tx];
            acc[0][0] += a2.x * b2.x; acc[0][1] += a2.x * b2.y;
            acc[1][0] += a2.y * b2.x; acc[1][1] += a2.y * b2.y;
        }
        __syncthreads();
    }
#pragma unroll
    for (int m = 1; m < 8; m <<= 1) sn += __shfl_xor(sn, m, 64);
    if ((st & 7) == 0) { if (isX) nX[lr0] = sn; else nY[lr0] = sn; }
    __syncthreads();

    int i0 = by * 64 + 2 * ty, j0 = bx * 64 + 2 * tx;
    float vy0 = 1.0f / sqrtf(nY[2 * tx + 0]);
    float vy1 = 1.0f / sqrtf(nY[2 * tx + 1]);
#pragma unroll
    for (int r = 0; r < 2; ++r) {
        float vx = 1.0f / sqrtf(nX[2 * ty + r]);
        float2 o;
        o.x = acc[r][0] * vx * vy0 - 1.0f;  // Cl = dot - 1 = -C
        o.y = acc[r][1] * vx * vy1 - 1.0f;
        *(float2*)(Cl + (size_t)(i0 + r) * 1024 + j0) = o;
    }
}

// ---------------------- persistent IPOT iteration --------------------------
__global__ __launch_bounds__(1024)
void k_ipot(float* __restrict__ ws, float* __restrict__ out) {
    __shared__ float sLp[1056];        // s (loop) / b (epilogue): [u][l], stride 66
    __shared__ float buf[16 * 1056];   // col partials [wave][u*66+lane]; epi Ps/Rs
    __shared__ float twv[16];
    __shared__ float pad[2600];        // occupancy shaper: LDS > 80KB -> 1 WG/CU
                                       // -> 4 waves/EU allocator budget (R10)

    const int g = blockIdx.x, tid = threadIdx.x;
    const int rs = tid >> 6, lane = tid & 63;   // wave id (0..15) / lane
    const int uo = tid & 15, lo = tid >> 4;     // owned col tid = lo*16+uo
    float* Cl   = ws + CL_OFF;
    float* cvec = ws + CVEC_OFF;
    unsigned* flg = (unsigned*)(ws + FLG_OFF);

    pad[tid & 2047] = 0.0f;  // keep pad allocated; read (exact +0.0) at end

    // thread owns rows g*32 + rs*2 + i (i<2), cols lane*16 + u (u<16)
    const float* csrc0 = Cl + (size_t)(g * 32 + rs * 2 + 0) * 1024 + lane * 16;
    const float* csrc1 = csrc0 + 1024;

    float E[2][16];
    float p0 = 0.0f, p1 = 0.0f;   // rowsum(Cl) for epilogue (C not kept)
#pragma unroll
    for (int q = 0; q < 4; ++q) {
        float4 c0 = *(const float4*)(csrc0 + 4 * q);
        float4 c1 = *(const float4*)(csrc1 + 4 * q);
        p0 += c0.x + c0.y + c0.z + c0.w;
        p1 += c1.x + c1.y + c1.z + c1.w;
        E[0][4 * q + 0] = __expf(c0.x); E[0][4 * q + 1] = __expf(c0.y);
        E[0][4 * q + 2] = __expf(c0.z); E[0][4 * q + 3] = __expf(c0.w);
        E[1][4 * q + 0] = __expf(c1.x); E[1][4 * q + 1] = __expf(c1.y);
        E[1][4 * q + 2] = __expf(c1.z); E[1][4 * q + 3] = __expf(c1.w);
    }

    float bv = 1.0f;            // b_prev for owned col (= tid)
    float a0 = 0.0f, a1 = 0.0f; // this wave's row scalings (all lanes)

    for (int t = 0; t < NIT; ++t) {
        float sval;
        if (t == 0) {
            sval = 1.0f / 1024.0f;
        } else {
            // wave 0 polls all 32 per-WG flags (iter t-1 done => flg >= t)
            if (rs == 0) {
                const unsigned* fb = flg + (lane & 31);
                const unsigned tgt = (unsigned)t;
                long gd = 0;
                for (;;) {
                    unsigned v = __hip_atomic_load(fb, __ATOMIC_RELAXED,
                                                   __HIP_MEMORY_SCOPE_AGENT);
                    if (__all(v >= tgt)) break;
                    if (++gd > 2000000) break;  // anti-hang bailout
                    __builtin_amdgcn_s_sleep(1);
                }
            }
            __syncthreads();
            // one-shot guaranteed-ready readback: 8 replicas at own column
            const float* rb = cvec + ((t + 2) % 3) * (NREP * 1024) + tid;
            float r0 = __hip_atomic_load(rb + 0 * 1024, __ATOMIC_RELAXED, __HIP_MEMORY_SCOPE_AGENT);
            float r1 = __hip_atomic_load(rb + 1 * 1024, __ATOMIC_RELAXED, __HIP_MEMORY_SCOPE_AGENT);
            float r2 = __hip_atomic_load(rb + 2 * 1024, __ATOMIC_RELAXED, __HIP_MEMORY_SCOPE_AGENT);
            float r3 = __hip_atomic_load(rb + 3 * 1024, __ATOMIC_RELAXED, __HIP_MEMORY_SCOPE_AGENT);
            float r4 = __hip_atomic_load(rb + 4 * 1024, __ATOMIC_RELAXED, __HIP_MEMORY_SCOPE_AGENT);
            float r5 = __hip_atomic_load(rb + 5 * 1024, __ATOMIC_RELAXED, __HIP_MEMORY_SCOPE_AGENT);
            float r6 = __hip_atomic_load(rb + 6 * 1024, __ATOMIC_RELAXED, __HIP_MEMORY_SCOPE_AGENT);
            float r7 = __hip_atomic_load(rb + 7 * 1024, __ATOMIC_RELAXED, __HIP_MEMORY_SCOPE_AGENT);
            if (t >= 2 && tid < 128) {  // zero buffer (t+1)%3 (read at t-1, done)
                ull* zb = (ull*)(cvec + ((t + 1) % 3) * (NREP * 1024)) + g * 128 + tid;
                __hip_atomic_store(zb, 0ull, __ATOMIC_RELAXED, __HIP_MEMORY_SCOPE_AGENT);
            }
            float c = r0 + r1 + r2 + r3 + r4 + r5 + r6 + r7;
            float b = 1.0f / c;
            sval = b * b / bv * (1.0f / 1024.0f);  // 2^-10 inj
            bv = b;
        }
        sLp[uo * 66 + lo] = sval;   // s for col tid at [tid&15][tid>>4]
        __syncthreads();

        // row phase: rp[i] = sum_u E[i][u] * s[lane*16+u]; xor-reduce -> all lanes
        float sv[16];
#pragma unroll
        for (int u = 0; u < 16; ++u) sv[u] = sLp[u * 66 + lane];
        float rp0 = 0.0f, rp1 = 0.0f;
#pragma unroll
        for (int u = 0; u < 16; ++u) {
            rp0 += E[0][u] * sv[u];
            rp1 += E[1][u] * sv[u];
        }
#pragma unroll
        for (int m = 1; m < 64; m <<= 1) {
            rp0 += __shfl_xor(rp0, m, 64);
            rp1 += __shfl_xor(rp1, m, 64);
        }
        a0 = 1.0f / (1024.0f * rp0);
        a1 = 1.0f / (1024.0f * rp1);

        // col phase: this wave's 2-row partials for its 16 cols (padded layout)
#pragma unroll
        for (int u = 0; u < 16; ++u)
            buf[rs * 1056 + u * 66 + lane] = E[0][u] * a0 + E[1][u] * a1;
        __syncthreads();

        // owner (col tid): sum 16 wave-partials, atomicAdd to replica g&7
        float csum = 0.0f;
#pragma unroll
        for (int w = 0; w < 16; ++w) csum += buf[w * 1056 + uo * 66 + lo];
        atomicAdd(cvec + (t % 3) * (NREP * 1024) + (g & 7) * 1024 + tid, csum);
        __syncthreads();  // per-thread vmcnt drain: adds + zero stores at LLC
        if (tid == 0)     // readiness: ONE plain store to own flag (no RMW)
            __hip_atomic_store(&flg[g], (unsigned)(t + 1),
                               __ATOMIC_RELAXED, __HIP_MEMORY_SCOPE_AGENT);

        // recompute E for next round: reload Cl (L2-hot) in the skew shadow
        if (t < NIT - 1) {
            const float kf = (float)(t + 2);
#pragma unroll
            for (int q = 0; q < 4; ++q) {
                float4 c0 = *(const float4*)(csrc0 + 4 * q);
                float4 c1 = *(const float4*)(csrc1 + 4 * q);
                E[0][4 * q + 0] = __expf(kf * c0.x); E[0][4 * q + 1] = __expf(kf * c0.y);
                E[0][4 * q + 2] = __expf(kf * c0.z); E[0][4 * q + 3] = __expf(kf * c0.w);
                E[1][4 * q + 0] = __expf(kf * c1.x); E[1][4 * q + 1] = __expf(kf * c1.y);
                E[1][4 * q + 2] = __expf(kf * c1.z); E[1][4 * q + 3] = __expf(kf * c1.w);
            }
        }
    }

    // ------------- epilogue: E = exp(50*Cl), a0/a1 = round-49 a -------------
    if (rs == 0) {  // wait for all WGs' iter-49 adds
        const unsigned* fb = flg + (lane & 31);
        long gd = 0;
        for (;;) {
            unsigned v = __hip_atomic_load(fb, __ATOMIC_RELAXED,
                                           __HIP_MEMORY_SCOPE_AGENT);
            if (__all(v >= (unsigned)NIT)) break;
            if (++gd > 2000000) break;
            __builtin_amdgcn_s_sleep(1);
        }
    }
    __syncthreads();
    {   // final b for owned col: one-shot readback of iter-49 replicas
        const float* rb = cvec + ((NIT - 1) % 3) * (NREP * 1024) + tid;
        float r0 = __hip_atomic_load(rb + 0 * 1024, __ATOMIC_RELAXED, __HIP_MEMORY_SCOPE_AGENT);
        float r1 = __hip_atomic_load(rb + 1 * 1024, __ATOMIC_RELAXED, __HIP_MEMORY_SCOPE_AGENT);
        float r2 = __hip_atomic_load(rb + 2 * 1024, __ATOMIC_RELAXED, __HIP_MEMORY_SCOPE_AGENT);
        float r3 = __hip_atomic_load(rb + 3 * 1024, __ATOMIC_RELAXED, __HIP_MEMORY_SCOPE_AGENT);
        float r4 = __hip_atomic_load(rb + 4 * 1024, __ATOMIC_RELAXED, __HIP_MEMORY_SCOPE_AGENT);
        float r5 = __hip_atomic_load(rb + 5 * 1024, __ATOMIC_RELAXED, __HIP_MEMORY_SCOPE_AGENT);
        float r6 = __hip_atomic_load(rb + 6 * 1024, __ATOMIC_RELAXED, __HIP_MEMORY_SCOPE_AGENT);
        float r7 = __hip_atomic_load(rb + 7 * 1024, __ATOMIC_RELAXED, __HIP_MEMORY_SCOPE_AGENT);
        sLp[uo * 66 + lo] = 1.0f / (r0 + r1 + r2 + r3 + r4 + r5 + r6 + r7);
    }
    __syncthreads();

    // P(k,A=lane) and R(k,B=lane) for this thread's 2 rows (A-block == lane)
    float* Ps = buf;          // [32][64]
    float* Rs = buf + 2048;   // [32][64]
    float bl[16];
#pragma unroll
    for (int u = 0; u < 16; ++u) bl[u] = sLp[u * 66 + lane];
    {
        float r0 = 0.0f, r1 = 0.0f;
#pragma unroll
        for (int u = 0; u < 16; ++u) {
            r0 += E[0][u] * bl[u];
            r1 += E[1][u] * bl[u];
        }
        Ps[(rs * 2 + 0) * 64 + lane] = -p0;            // C = -Cl, p = rowsum(Cl)
        Rs[(rs * 2 + 0) * 64 + lane] = a0 * r0;
        Ps[(rs * 2 + 1) * 64 + lane] = -p1;
        Rs[(rs * 2 + 1) * 64 + lane] = a1 * r1;
    }
    __syncthreads();

    // G partial (this WG's 32 k-rows) -> atomicAdd into zeroed d_out
    float Rk[32];
#pragma unroll
    for (int k = 0; k < 32; ++k) Rk[k] = Rs[k * 64 + lane];  // B = lane
    const float sc = 1.0f / (256.0f * 1024.0f);
    float tsum = pad[tid & 2047];   // exact +0.0; keeps pad live
#pragma unroll
    for (int q = 0; q < 4; ++q) {
        int o = tid + 1024 * q;
        int A = o >> 6;  // = rs + 16*q
        float acc = 0.0f;
#pragma unroll
        for (int k = 0; k < 32; ++k) acc += Ps[k * 64 + A] * Rk[k];
        float val = acc * sc;
        atomicAdd(out + o, val);
        if (A == lane) tsum += val;
    }
#pragma unroll
    for (int m = 1; m < 64; m <<= 1) tsum += __shfl_xor(tsum, m, 64);
    if (lane == 0) twv[rs] = tsum;
    __syncthreads();
    if (tid == 0) {
        float ts = 0.0f;
#pragma unroll
        for (int w = 0; w < 16; ++w) ts += twv[w];
        atomicAdd(out + 4096, ts);
    }
}

// ---------------------------------------------------------------------------
extern "C" void kernel_launch(void* const* d_in, const int* in_sizes, int n_in,
                              void* d_out, int out_size, void* d_ws, size_t ws_size,
                              hipStream_t stream) {
    const float* X = (const float*)d_in[0];  // t_prob [1024,512]
    const float* Y = (const float*)d_in[1];  // v_prob [1024,512]
    float* out = (float*)d_out;              // [64*64 + 1]
    float* ws  = (float*)d_ws;

    // zero cvec + flags (ws poisoned each call), zero d_out
    (void)hipMemsetAsync((char*)d_ws + (size_t)CVEC_OFF * 4, 0,
                         (size_t)(3 * NREP * 1024 + 64) * 4, stream);
    (void)hipMemsetAsync(d_out, 0, (size_t)out_size * 4, stream);

    k_gemm<<<dim3(16, 16), 1024, 0, stream>>>(X, Y, ws);
    k_ipot<<<NWG, TPB, 0, stream>>>(ws, out);
}